// Round 7
// baseline (825.790 us; speedup 1.0000x reference)
//
#include <hip/hip_runtime.h>

#define HID 128
#define NLAYER 4

typedef unsigned short u16;
typedef __attribute__((ext_vector_type(8))) unsigned short u16x8;
typedef __attribute__((ext_vector_type(8))) short short8;
typedef __attribute__((ext_vector_type(4))) float floatx4;

__device__ __forceinline__ float bf2f(u16 u) {
    union { unsigned int i; float f; } v; v.i = ((unsigned int)u) << 16; return v.f;
}
__device__ __forceinline__ u16 f2bf(float f) {
    union { float f; unsigned int i; } v; v.f = f;
    unsigned int r = v.i + 0x7FFFu + ((v.i >> 16) & 1u);
    return (u16)(r >> 16);
}

// ---------------------------------------------------------------------------
__device__ __forceinline__ int lowbound(const int* __restrict__ a, int n, int v) {
    int lo = 0, hi = n;
    while (lo < hi) {
        int mid = (lo + hi) >> 1;
        if (a[mid] < v) lo = mid + 1; else hi = mid;
    }
    return lo;
}

// ---------------------------------------------------------------------------
// Weight prep: fp32 -> bf16, transposed to [enc][l][n][k].
// ---------------------------------------------------------------------------
__global__ void prep_weights(const float* __restrict__ W1, const float* __restrict__ W2,
                             u16* __restrict__ W1t, u16* __restrict__ W2t) {
    const int T = 3 * NLAYER * 128 * 256;  // 393216
    int o = blockIdx.x * blockDim.x + threadIdx.x;
    if (o < T) {
        int k = o & 127, n = (o >> 7) & 255, el = o >> 15;
        W1t[o] = f2bf(W1[((size_t)el * 128 + k) * 256 + n]);
    } else if (o < 2 * T) {
        int o2 = o - T;
        int k = o2 & 255, n = (o2 >> 8) & 127, el = o2 >> 15;
        W2t[o2] = f2bf(W2[((size_t)el * 256 + k) * 128 + n]);
    }
}

// ---------------------------------------------------------------------------
// XCD-binned histogram (round-6: part of the -45us win; same mechanism as
// fill2b — each dst-bin's count slice stays in one XCD's L2).
// ---------------------------------------------------------------------------
__global__ __launch_bounds__(256) void hist2b(const int* __restrict__ de,
                                              const int* __restrict__ se,
                                              int* __restrict__ cntd, int* __restrict__ cnts,
                                              int Ed, int Es, int N) {
    const int g = blockIdx.y;
    const int* ei = g ? se : de;
    int* cnt = g ? cnts : cntd;
    const int E = g ? Es : Ed;
    const int nchunk = gridDim.x >> 3;
    const int bin = blockIdx.x & 7;
    const int chunk = blockIdx.x >> 3;
    const int BS = (N + 7) >> 3;
    const int dlo = bin * BS;
    const int dhi = min(N, dlo + BS);
    const int ce = (E + nchunk - 1) / nchunk;
    const int elo = chunk * ce;
    const int ehi = min(E, elo + ce);
    for (int e = elo + (int)threadIdx.x; e < ehi; e += 256) {
        const int dst = ei[E + e];
        if (dst >= dlo && dst < dhi) atomicAdd(&cnt[dst], 1);
    }
}

__global__ __launch_bounds__(256) void scan1v(const int* __restrict__ cntd,
                                              const int* __restrict__ cnts,
                                              int* __restrict__ bsumd,
                                              int* __restrict__ bsums, int N) {
    const int g = blockIdx.y;
    const int* cnt = g ? cnts : cntd;
    int* bsum = g ? bsums : bsumd;
    __shared__ int s[256];
    int i = blockIdx.x * 256 + threadIdx.x;
    s[threadIdx.x] = (i < N) ? cnt[i] : 0;
    __syncthreads();
    for (int o = 128; o > 0; o >>= 1) {
        if (threadIdx.x < o) s[threadIdx.x] += s[threadIdx.x + o];
        __syncthreads();
    }
    if (threadIdx.x == 0) bsum[blockIdx.x] = s[0];
}

__global__ __launch_bounds__(256) void scan2v(int* __restrict__ bsumd,
                                              int* __restrict__ bsums, int nb) {
    int* bsum = blockIdx.x ? bsums : bsumd;
    __shared__ int s[256];
    __shared__ int carry;
    if (threadIdx.x == 0) carry = 0;
    __syncthreads();
    for (int base = 0; base < nb; base += 256) {
        int i = base + threadIdx.x;
        int v = (i < nb) ? bsum[i] : 0;
        s[threadIdx.x] = v;
        __syncthreads();
        for (int o = 1; o < 256; o <<= 1) {
            int tv = (threadIdx.x >= o) ? s[threadIdx.x - o] : 0;
            __syncthreads();
            s[threadIdx.x] += tv;
            __syncthreads();
        }
        int excl = carry + s[threadIdx.x] - v;
        if (i < nb) bsum[i] = excl;
        __syncthreads();
        if (threadIdx.x == 0) carry += s[255];
        __syncthreads();
    }
}

// scan3v seeds the fill cursors (cur = rowptr start), so the fill needs
// only ONE atomic per edge (no separate rowptr read + counter).
__global__ __launch_bounds__(256) void scan3v(const int* __restrict__ cntd,
                                              const int* __restrict__ cnts,
                                              const int* __restrict__ bsumd,
                                              const int* __restrict__ bsums,
                                              int* __restrict__ rpd, int* __restrict__ rps,
                                              int* __restrict__ curd, int* __restrict__ curs,
                                              int N, int Ed, int Es) {
    const int g = blockIdx.y;
    const int* cnt = g ? cnts : cntd;
    const int* bsum = g ? bsums : bsumd;
    int* rowptr = g ? rps : rpd;
    int* cur = g ? curs : curd;
    const int E = g ? Es : Ed;
    __shared__ int s[256];
    int i = blockIdx.x * 256 + threadIdx.x;
    int v = (i < N) ? cnt[i] : 0;
    s[threadIdx.x] = v;
    __syncthreads();
    for (int o = 1; o < 256; o <<= 1) {
        int tv = (threadIdx.x >= o) ? s[threadIdx.x - o] : 0;
        __syncthreads();
        s[threadIdx.x] += tv;
        __syncthreads();
    }
    if (i < N) {
        const int st = bsum[blockIdx.x] + s[threadIdx.x] - v;
        rowptr[i] = st;
        cur[i] = st;
    }
    if (i == 0 && blockIdx.x == 0) rowptr[N] = E;
}

// ---------------------------------------------------------------------------
// XCD-binned CSR fill (round-2 verified win).
// ---------------------------------------------------------------------------
__global__ __launch_bounds__(256) void fill2b(const int* __restrict__ de,
                                              const int* __restrict__ se,
                                              int* __restrict__ curd, int* __restrict__ curs,
                                              int* __restrict__ sid, int* __restrict__ sis,
                                              int Ed, int Es, int N) {
    const int g = blockIdx.y;
    const int* ei = g ? se : de;
    int* cur = g ? curs : curd;
    int* srcidx = g ? sis : sid;
    const int E = g ? Es : Ed;
    const int nchunk = gridDim.x >> 3;
    const int bin = blockIdx.x & 7;
    const int chunk = blockIdx.x >> 3;
    const int BS = (N + 7) >> 3;
    const int dlo = bin * BS;
    const int dhi = min(N, dlo + BS);
    const int ce = (E + nchunk - 1) / nchunk;
    const int elo = chunk * ce;
    const int ehi = min(E, elo + ce);
    for (int e = elo + (int)threadIdx.x; e < ehi; e += 256) {
        const int dst = ei[E + e];
        if (dst >= dlo && dst < dhi) {
            const int pos = atomicAdd(&cur[dst], 1);
            srcidx[pos] = ei[e];
        }
    }
}

// ---------------------------------------------------------------------------
// Atom encoder: h = x @ aW + ab  (fp32 compute, bf16 store). grid.z = slot.
// Flat layout [slot][N][128].
// ---------------------------------------------------------------------------
__global__ void atom_kernel(const float* __restrict__ dx, const float* __restrict__ sx,
                            const float* __restrict__ aW, const float* __restrict__ ab,
                            u16* __restrict__ h, int N) {
    const int slot = blockIdx.z;
    long idx = (long)blockIdx.x * blockDim.x + threadIdx.x;
    if (idx >= (long)N * HID) return;
    const int n = (int)(idx / HID), c = (int)(idx % HID);
    const float* x = (slot < 2) ? dx : sx;
    const float* W = aW + (size_t)slot * 9 * HID;
    float acc = ab[slot * HID + c];
#pragma unroll
    for (int k = 0; k < 9; k++) acc = fmaf(x[n * 9 + k], W[k * HID + c], acc);
    h[(size_t)slot * N * HID + idx] = f2bf(acc);
}

// ---------------------------------------------------------------------------
// Gather-aggregate: z[n] = (1+eps)*h[n] + sum h[src].  ROUND-2 EXACT.
// At its random-access roofline (3.76 TB/s effective). Do not touch.
// ---------------------------------------------------------------------------
__global__ __launch_bounds__(256) void gather_agg(
    const int* __restrict__ rpd, const int* __restrict__ sid,
    const int* __restrict__ rps, const int* __restrict__ sis,
    const u16* __restrict__ h, u16* __restrict__ z,
    const float* __restrict__ eps, int N, int l) {
    const int slot = blockIdx.z;
    const int node = blockIdx.x * 16 + (threadIdx.x >> 4);
    if (node >= N) return;
    const int lane = threadIdx.x & 63;
    const int sl = lane & 15;
    const int subbase = lane & 48;  // 16-lane subgroup base within wave
    const int* rowptr = (slot < 2) ? rpd : rps;
    const int* srcidx = (slot < 2) ? sid : sis;
    const int lo = rowptr[node], hi = rowptr[node + 1];
    const u16* hp = h + (size_t)slot * N * HID;
    const int coff = sl * 8;

    u16x8 hv = *(const u16x8*)(hp + (size_t)node * HID + coff);
    const float scale = 1.f + eps[slot * NLAYER + l];
    float s[8];
#pragma unroll
    for (int i = 0; i < 8; i++) s[i] = bf2f(hv[i]) * scale;

    for (int base = lo; base < hi; base += 16) {
        const int cnt = min(16, hi - base);
        int idx = (sl < cnt) ? srcidx[base + sl] : 0;
        int j = 0;
        for (; j + 4 <= cnt; j += 4) {
            const int s0 = __shfl(idx, subbase + j);
            const int s1 = __shfl(idx, subbase + j + 1);
            const int s2 = __shfl(idx, subbase + j + 2);
            const int s3 = __shfl(idx, subbase + j + 3);
            u16x8 v0 = *(const u16x8*)(hp + (size_t)s0 * HID + coff);
            u16x8 v1 = *(const u16x8*)(hp + (size_t)s1 * HID + coff);
            u16x8 v2 = *(const u16x8*)(hp + (size_t)s2 * HID + coff);
            u16x8 v3 = *(const u16x8*)(hp + (size_t)s3 * HID + coff);
#pragma unroll
            for (int i = 0; i < 8; i++)
                s[i] += (bf2f(v0[i]) + bf2f(v1[i])) + (bf2f(v2[i]) + bf2f(v3[i]));
        }
        for (; j < cnt; j++) {
            const int sj = __shfl(idx, subbase + j);
            u16x8 v = *(const u16x8*)(hp + (size_t)sj * HID + coff);
#pragma unroll
            for (int i = 0; i < 8; i++) s[i] += bf2f(v[i]);
        }
    }
    u16x8 o;
#pragma unroll
    for (int i = 0; i < 8; i++) o[i] = f2bf(s[i]);
    *(u16x8*)(z + (size_t)slot * N * HID + (size_t)node * HID + coff) = o;
}

// ---------------------------------------------------------------------------
// Fused GIN layer: h_out = relu(BN2( relu(BN1(z@W1+b1)) @ W2 + b2 ))
// ROUND-2 EXACT (A/B isolation: round-6 bundled hist2b + LDS weight staging;
// per-dispatch rocprof suggested staging regressed 61->75us but cross-round
// clock skew makes that unreliable — this round isolates it). The in-loop
// global B loads are software-pipelined by the compiler across the unrolled
// ks loop; LDS stays 34.8KB.
// MFMA 16x16x32 bf16, C/D: col=lane&15, row=(lane>>4)*4+reg [m89-verified].
// ---------------------------------------------------------------------------
__global__ __launch_bounds__(256, 2) void fused_layer(
    const u16* __restrict__ A, const u16* __restrict__ W1t, const u16* __restrict__ W2t,
    const float* __restrict__ b1, const float* __restrict__ g1, const float* __restrict__ be1,
    const float* __restrict__ m1, const float* __restrict__ v1,
    const float* __restrict__ b2, const float* __restrict__ g2, const float* __restrict__ be2,
    const float* __restrict__ m2, const float* __restrict__ v2,
    u16* __restrict__ out, int M, int l) {

    const int slot = blockIdx.z;
    const int m0 = blockIdx.x * 128;
    const u16* Ap  = A + (size_t)slot * M * 128;
    const int el = slot * NLAYER + l;
    const u16* Wp1 = W1t + (size_t)el * (256 * 128);
    const u16* Wp2 = W2t + (size_t)el * (128 * 256);
    const size_t poff1 = (size_t)el * 256;
    const size_t poff2 = (size_t)el * 128;

    __shared__ u16 sm[128 * 136];  // 34.8 KB, reused for z then z2 halves

    const int tid = threadIdx.x;
    const int lane = tid & 63;
    const int w = tid >> 6;
    const int sl = lane & 15;
    const int k8 = lane >> 4;

    // ---- stage z tile ----
    {
        const int rp = tid >> 4;
        const int kc = (tid & 15) * 8;
#pragma unroll
        for (int p = 0; p < 8; p++) {
            const int row = p * 16 + rp;
            int gr = m0 + row; if (gr >= M) gr = M - 1;
            *(uint4*)&sm[row * 136 + kc] = *(const uint4*)(Ap + (size_t)gr * 128 + kc);
        }
    }
    __syncthreads();

    // ---- GEMM1: 128 x 256, K=128 ----
    floatx4 acc1[8][4];
#pragma unroll
    for (int mt = 0; mt < 8; mt++)
#pragma unroll
        for (int c = 0; c < 4; c++) acc1[mt][c] = (floatx4)0.f;

#pragma unroll
    for (int ks = 0; ks < 4; ks++) {
        short8 a[8], b[4];
#pragma unroll
        for (int mt = 0; mt < 8; mt++)
            a[mt] = *(const short8*)&sm[(mt * 16 + sl) * 136 + ks * 32 + k8 * 8];
#pragma unroll
        for (int c = 0; c < 4; c++) {
            const int n = (c * 4 + w) * 16 + sl;
            b[c] = *(const short8*)(Wp1 + (size_t)n * 128 + ks * 32 + k8 * 8);
        }
#pragma unroll
        for (int mt = 0; mt < 8; mt++)
#pragma unroll
            for (int c = 0; c < 4; c++)
                acc1[mt][c] = __builtin_amdgcn_mfma_f32_16x16x32_bf16(a[mt], b[c], acc1[mt][c], 0, 0, 0);
    }
    __syncthreads();  // all waves done reading z tile

    // ---- z2 halves + GEMM2 ----
    const int wr = w & 1, wc = w >> 1;
    floatx4 acc2[4][4];
#pragma unroll
    for (int mt = 0; mt < 4; mt++)
#pragma unroll
        for (int nt = 0; nt < 4; nt++) acc2[mt][nt] = (floatx4)0.f;

#pragma unroll
    for (int part = 0; part < 2; part++) {
        // write z2 cols [part*128, part*128+128) after BN1+ReLU
#pragma unroll
        for (int c = part * 2; c < part * 2 + 2; c++) {
            const int gcol = (c * 4 + w) * 16 + sl;
            const int lcol = gcol - part * 128;
            const float sc = g1[poff1 + gcol] * rsqrtf(v1[poff1 + gcol] + 1e-5f);
            const float sh = (b1[poff1 + gcol] - m1[poff1 + gcol]) * sc + be1[poff1 + gcol];
#pragma unroll
            for (int mt = 0; mt < 8; mt++) {
#pragma unroll
                for (int r = 0; r < 4; r++) {
                    const int m = mt * 16 + k8 * 4 + r;
                    sm[m * 136 + lcol] = f2bf(fmaxf(fmaf(acc1[mt][c][r], sc, sh), 0.f));
                }
            }
        }
        __syncthreads();
        // GEMM2 over this K half
#pragma unroll
        for (int ks = 0; ks < 4; ks++) {
            short8 a[4], b[4];
#pragma unroll
            for (int mt = 0; mt < 4; mt++)
                a[mt] = *(const short8*)&sm[(wr * 64 + mt * 16 + sl) * 136 + ks * 32 + k8 * 8];
#pragma unroll
            for (int nt = 0; nt < 4; nt++) {
                const int n = wc * 64 + nt * 16 + sl;
                b[nt] = *(const short8*)(Wp2 + (size_t)n * 256 + part * 128 + ks * 32 + k8 * 8);
            }
#pragma unroll
            for (int mt = 0; mt < 4; mt++)
#pragma unroll
                for (int nt = 0; nt < 4; nt++)
                    acc2[mt][nt] = __builtin_amdgcn_mfma_f32_16x16x32_bf16(a[mt], b[nt], acc2[mt][nt], 0, 0, 0);
        }
        if (part == 0) __syncthreads();  // before overwriting z2 buffer
    }

    // ---- BN2 + ReLU epilogue ----
    u16* outp = out + (size_t)slot * M * 128;
#pragma unroll
    for (int nt = 0; nt < 4; nt++) {
        const int col = wc * 64 + nt * 16 + sl;
        const float sc = g2[poff2 + col] * rsqrtf(v2[poff2 + col] + 1e-5f);
        const float sh = (b2[poff2 + col] - m2[poff2 + col]) * sc + be2[poff2 + col];
#pragma unroll
        for (int mt = 0; mt < 4; mt++) {
#pragma unroll
            for (int r = 0; r < 4; r++) {
                const int gr = m0 + wr * 64 + mt * 16 + k8 * 4 + r;
                if (gr < M)
                    outp[(size_t)gr * 128 + col] = f2bf(fmaxf(fmaf(acc2[mt][nt][r], sc, sh), 0.f));
            }
        }
    }
}

// ---------------------------------------------------------------------------
// Segment-mean pool (bat sorted). bf16 in, fp32 out.
// ---------------------------------------------------------------------------
__global__ __launch_bounds__(128) void pool_kernel(const int* __restrict__ db,
                                                   const int* __restrict__ sb,
                                                   const u16* __restrict__ h,
                                                   float* __restrict__ emb,
                                                   int N, int B) {
    const int slot = blockIdx.z;
    const int* bat = (slot < 2) ? db : sb;
    const int g = blockIdx.x;
    const int lo = lowbound(bat, N, g);
    const int hi = lowbound(bat, N, g + 1);
    const int c = threadIdx.x;
    float s = 0.f;
    const u16* hp = h + (size_t)slot * N * HID;
    for (int n = lo; n < hi; n++) s += bf2f(hp[(size_t)n * HID + c]);
    const float cnt = (float)(hi - lo);
    emb[((size_t)slot * B + g) * HID + c] = s / fmaxf(cnt, 1.f);
}

// ---------------------------------------------------------------------------
__device__ __forceinline__ float block_sum128(float x, float* red, int tid) {
    red[tid] = x;
    __syncthreads();
    if (tid < 64) {
        float v = red[tid] + red[tid + 64];
#pragma unroll
        for (int o = 32; o > 0; o >>= 1) v += __shfl_down(v, o);
        if (tid == 0) red[0] = v;
    }
    __syncthreads();
    float r = red[0];
    __syncthreads();
    return r;
}

// ---------------------------------------------------------------------------
// Fusion head (fp32)
// ---------------------------------------------------------------------------
__global__ __launch_bounds__(128) void fusion_kernel(
    const float* __restrict__ emb, const float* __restrict__ t,
    const float* __restrict__ tW1, const float* __restrict__ tb1,
    const float* __restrict__ tW2, const float* __restrict__ tb2,
    const float* __restrict__ iW, const float* __restrict__ ib,
    const float* __restrict__ ilg, const float* __restrict__ ilb,
    const float* __restrict__ fW1, const float* __restrict__ fb1,
    const float* __restrict__ l1g, const float* __restrict__ l1b,
    const float* __restrict__ fW2, const float* __restrict__ fb2,
    const float* __restrict__ l2g, const float* __restrict__ l2b,
    const float* __restrict__ fW3, const float* __restrict__ fb3,
    float* __restrict__ out, int B) {
    const int r = blockIdx.x;
    const int tid = threadIdx.x;
    __shared__ float cs[256];
    __shared__ float cat[288];
    __shared__ float buf[128];
    __shared__ float red[128];
    __shared__ float tmp32[32];

    cs[tid]        = emb[((size_t)1 * B + r) * HID + tid];
    cs[128 + tid]  = emb[((size_t)2 * B + r) * HID + tid];
    cat[tid]       = emb[((size_t)0 * B + r) * HID + tid];
    __syncthreads();

    float acc = ib[tid];
    for (int k = 0; k < 256; k++) acc = fmaf(cs[k], iW[k * HID + tid], acc);
    float mu  = block_sum128(acc, red, tid) * (1.f / 128.f);
    float d   = acc - mu;
    float var = block_sum128(d * d, red, tid) * (1.f / 128.f);
    float inter = fmaxf(d * rsqrtf(var + 1e-5f) * ilg[tid] + ilb[tid], 0.f);
    cat[128 + tid] = inter;

    if (tid < 32) tmp32[tid] = fmaxf(fmaf(t[r], tW1[tid], tb1[tid]), 0.f);
    __syncthreads();
    if (tid < 32) {
        float a2 = tb2[tid];
        for (int j = 0; j < 32; j++) a2 = fmaf(tmp32[j], tW2[j * 32 + tid], a2);
        cat[256 + tid] = a2;
    }
    __syncthreads();

    float a1 = fb1[tid];
    for (int k = 0; k < 288; k++) a1 = fmaf(cat[k], fW1[k * HID + tid], a1);
    mu  = block_sum128(a1, red, tid) * (1.f / 128.f);
    d   = a1 - mu;
    var = block_sum128(d * d, red, tid) * (1.f / 128.f);
    buf[tid] = fmaxf(d * rsqrtf(var + 1e-5f) * l1g[tid] + l1b[tid], 0.f);
    __syncthreads();

    float a2v = 0.f;
    if (tid < 64) {
        a2v = fb2[tid];
        for (int k = 0; k < 128; k++) a2v = fmaf(buf[k], fW2[k * 64 + tid], a2v);
    }
    mu = block_sum128((tid < 64) ? a2v : 0.f, red, tid) * (1.f / 64.f);
    float d2 = (tid < 64) ? (a2v - mu) : 0.f;
    var = block_sum128(d2 * d2, red, tid) * (1.f / 64.f);
    float contrib = 0.f;
    if (tid < 64) {
        float h2 = fmaxf(d2 * rsqrtf(var + 1e-5f) * l2g[tid] + l2b[tid], 0.f);
        contrib = h2 * fW3[tid];
    }
    float s = block_sum128(contrib, red, tid);
    if (tid == 0) out[r] = s + fb3[0];
}

// ---------------------------------------------------------------------------
extern "C" void kernel_launch(void* const* d_in, const int* in_sizes, int n_in,
                              void* d_out, int out_size, void* d_ws, size_t ws_size,
                              hipStream_t stream) {
    const float* dx  = (const float*)d_in[0];
    const int*   de  = (const int*)d_in[1];
    const int*   db  = (const int*)d_in[2];
    const float* sx  = (const float*)d_in[3];
    const int*   se  = (const int*)d_in[4];
    const int*   sb  = (const int*)d_in[5];
    const float* t   = (const float*)d_in[6];
    const float* aW  = (const float*)d_in[7];
    const float* ab  = (const float*)d_in[8];
    const float* eps = (const float*)d_in[9];
    const float* W1  = (const float*)d_in[10];
    const float* b1  = (const float*)d_in[11];
    const float* g1  = (const float*)d_in[12];
    const float* be1 = (const float*)d_in[13];
    const float* m1  = (const float*)d_in[14];
    const float* v1  = (const float*)d_in[15];
    const float* W2  = (const float*)d_in[16];
    const float* b2  = (const float*)d_in[17];
    const float* g2  = (const float*)d_in[18];
    const float* be2 = (const float*)d_in[19];
    const float* m2  = (const float*)d_in[20];
    const float* v2  = (const float*)d_in[21];
    const float* tW1 = (const float*)d_in[22];
    const float* tb1 = (const float*)d_in[23];
    const float* tW2 = (const float*)d_in[24];
    const float* tb2 = (const float*)d_in[25];
    const float* iW  = (const float*)d_in[26];
    const float* ib  = (const float*)d_in[27];
    const float* ilg = (const float*)d_in[28];
    const float* ilb = (const float*)d_in[29];
    const float* fW1 = (const float*)d_in[30];
    const float* fb1 = (const float*)d_in[31];
    const float* l1g = (const float*)d_in[32];
    const float* l1b = (const float*)d_in[33];
    const float* fW2 = (const float*)d_in[34];
    const float* fb2 = (const float*)d_in[35];
    const float* l2g = (const float*)d_in[36];
    const float* l2b = (const float*)d_in[37];
    const float* fW3 = (const float*)d_in[38];
    const float* fb3 = (const float*)d_in[39];
    float* out = (float*)d_out;

    const int N  = in_sizes[0] / 9;
    const int Ed = in_sizes[1] / 2;
    const int Es = in_sizes[4] / 2;
    const int B  = in_sizes[6];
    const int nb = (N + 255) / 256;

    // ---- workspace layout ----
    char* w8 = (char*)d_ws;
    int* rpd   = (int*)w8;
    int* rps   = rpd + (N + 1);
    int* cntd  = rps + (N + 1);
    int* cnts  = cntd + N;
    int* curd  = cnts + N;   // fill cursors (seeded by scan3v)
    int* curs  = curd + N;
    int* sid   = curs + N;
    int* sis   = sid + Ed;
    int* bsumd = sis + Es;
    int* bsums = bsumd + nb;
    size_t int_bytes = ((char*)(bsums + nb)) - w8;
    size_t foff = (int_bytes + 255) & ~(size_t)255;

    const int WT = 3 * NLAYER * 128 * 256;
    u16* W1t = (u16*)(w8 + foff);
    u16* W2t = W1t + WT;
    const size_t hS = (size_t)N * HID;
    u16* hbuf = W2t + WT;
    u16* zbuf = hbuf + 3 * hS;
    float* emb = (float*)(((uintptr_t)(zbuf + 3 * hS) + 255) & ~(uintptr_t)255);

    // ---- weight prep + CSR build ----
    prep_weights<<<(2 * WT + 255) / 256, 256, 0, stream>>>(W1, W2, W1t, W2t);
    hipMemsetAsync(cntd, 0, (size_t)2 * N * sizeof(int), stream);
    {
        dim3 gb(128 * 8, 2);  // 128 edge-chunks x 8 dst-bins, both graphs
        hist2b<<<gb, 256, 0, stream>>>(de, se, cntd, cnts, Ed, Es, N);
        dim3 gs1(nb, 2);
        scan1v<<<gs1, 256, 0, stream>>>(cntd, cnts, bsumd, bsums, N);
        scan2v<<<2, 256, 0, stream>>>(bsumd, bsums, nb);
        scan3v<<<gs1, 256, 0, stream>>>(cntd, cnts, bsumd, bsums, rpd, rps, curd, curs, N, Ed, Es);
        fill2b<<<gb, 256, 0, stream>>>(de, se, curd, curs, sid, sis, Ed, Es, N);
    }

    // ---- encoders (all 3 slots batched via grid.z) ----
    {
        dim3 ga((N * HID + 255) / 256, 1, 3);
        atom_kernel<<<ga, 256, 0, stream>>>(dx, sx, aW, ab, hbuf, N);
        for (int l = 0; l < NLAYER; l++) {
            dim3 gg((N + 15) / 16, 1, 3);
            gather_agg<<<gg, 256, 0, stream>>>(rpd, sid, rps, sis, hbuf, zbuf, eps, N, l);
            dim3 gf((N + 127) / 128, 1, 3);
            fused_layer<<<gf, 256, 0, stream>>>(zbuf, W1t, W2t,
                                                b1, g1, be1, m1, v1,
                                                b2, g2, be2, m2, v2,
                                                hbuf, N, l);
        }
        dim3 gp(B, 1, 3);
        pool_kernel<<<gp, 128, 0, stream>>>(db, sb, hbuf, emb, N, B);
    }
    fusion_kernel<<<B, 128, 0, stream>>>(emb, t, tW1, tb1, tW2, tb2,
                                         iW, ib, ilg, ilb, fW1, fb1, l1g, l1b,
                                         fW2, fb2, l2g, l2b, fW3, fb3, out, B);
}

// Round 8
// 772.881 us; speedup vs baseline: 1.0685x; 1.0685x over previous
//
#include <hip/hip_runtime.h>

#define HID 128
#define NLAYER 4

typedef unsigned short u16;
typedef __attribute__((ext_vector_type(8))) unsigned short u16x8;
typedef __attribute__((ext_vector_type(8))) short short8;
typedef __attribute__((ext_vector_type(4))) float floatx4;

__device__ __forceinline__ float bf2f(u16 u) {
    union { unsigned int i; float f; } v; v.i = ((unsigned int)u) << 16; return v.f;
}
__device__ __forceinline__ u16 f2bf(float f) {
    union { float f; unsigned int i; } v; v.f = f;
    unsigned int r = v.i + 0x7FFFu + ((v.i >> 16) & 1u);
    return (u16)(r >> 16);
}

// LDS-only barrier: cross-wave deps in fused_layer are exclusively through
// LDS, so we wait lgkmcnt(0) (ds ops) but deliberately NOT vmcnt — letting
// prefetched global loads stay in flight across the barrier (the compiler's
// __syncthreads() would drain vmcnt(0) and expose their latency; m97-ceiling
// pattern). Data-dependent vmcnt waits before each prefetch's ds_write are
// still auto-inserted by the compiler.
#define BARRIER_LDS() do { \
    asm volatile("s_waitcnt lgkmcnt(0)" ::: "memory"); \
    __builtin_amdgcn_s_barrier(); \
} while (0)

// ---------------------------------------------------------------------------
__device__ __forceinline__ int lowbound(const int* __restrict__ a, int n, int v) {
    int lo = 0, hi = n;
    while (lo < hi) {
        int mid = (lo + hi) >> 1;
        if (a[mid] < v) lo = mid + 1; else hi = mid;
    }
    return lo;
}

// ---------------------------------------------------------------------------
// Weight prep: fp32 -> bf16, transposed to [enc][l][n][k].
// ---------------------------------------------------------------------------
__global__ void prep_weights(const float* __restrict__ W1, const float* __restrict__ W2,
                             u16* __restrict__ W1t, u16* __restrict__ W2t) {
    const int T = 3 * NLAYER * 128 * 256;  // 393216
    int o = blockIdx.x * blockDim.x + threadIdx.x;
    if (o < T) {
        int k = o & 127, n = (o >> 7) & 255, el = o >> 15;
        W1t[o] = f2bf(W1[((size_t)el * 128 + k) * 256 + n]);
    } else if (o < 2 * T) {
        int o2 = o - T;
        int k = o2 & 255, n = (o2 >> 8) & 127, el = o2 >> 15;
        W2t[o2] = f2bf(W2[((size_t)el * 256 + k) * 128 + n]);
    }
}

// ---------------------------------------------------------------------------
// XCD-binned histogram (round-6/7: ~neutral but harmless; keeps the scattered
// atomics within one XCD's L2 slice).
// ---------------------------------------------------------------------------
__global__ __launch_bounds__(256) void hist2b(const int* __restrict__ de,
                                              const int* __restrict__ se,
                                              int* __restrict__ cntd, int* __restrict__ cnts,
                                              int Ed, int Es, int N) {
    const int g = blockIdx.y;
    const int* ei = g ? se : de;
    int* cnt = g ? cnts : cntd;
    const int E = g ? Es : Ed;
    const int nchunk = gridDim.x >> 3;
    const int bin = blockIdx.x & 7;
    const int chunk = blockIdx.x >> 3;
    const int BS = (N + 7) >> 3;
    const int dlo = bin * BS;
    const int dhi = min(N, dlo + BS);
    const int ce = (E + nchunk - 1) / nchunk;
    const int elo = chunk * ce;
    const int ehi = min(E, elo + ce);
    for (int e = elo + (int)threadIdx.x; e < ehi; e += 256) {
        const int dst = ei[E + e];
        if (dst >= dlo && dst < dhi) atomicAdd(&cnt[dst], 1);
    }
}

__global__ __launch_bounds__(256) void scan1v(const int* __restrict__ cntd,
                                              const int* __restrict__ cnts,
                                              int* __restrict__ bsumd,
                                              int* __restrict__ bsums, int N) {
    const int g = blockIdx.y;
    const int* cnt = g ? cnts : cntd;
    int* bsum = g ? bsums : bsumd;
    __shared__ int s[256];
    int i = blockIdx.x * 256 + threadIdx.x;
    s[threadIdx.x] = (i < N) ? cnt[i] : 0;
    __syncthreads();
    for (int o = 128; o > 0; o >>= 1) {
        if (threadIdx.x < o) s[threadIdx.x] += s[threadIdx.x + o];
        __syncthreads();
    }
    if (threadIdx.x == 0) bsum[blockIdx.x] = s[0];
}

__global__ __launch_bounds__(256) void scan2v(int* __restrict__ bsumd,
                                              int* __restrict__ bsums, int nb) {
    int* bsum = blockIdx.x ? bsums : bsumd;
    __shared__ int s[256];
    __shared__ int carry;
    if (threadIdx.x == 0) carry = 0;
    __syncthreads();
    for (int base = 0; base < nb; base += 256) {
        int i = base + threadIdx.x;
        int v = (i < nb) ? bsum[i] : 0;
        s[threadIdx.x] = v;
        __syncthreads();
        for (int o = 1; o < 256; o <<= 1) {
            int tv = (threadIdx.x >= o) ? s[threadIdx.x - o] : 0;
            __syncthreads();
            s[threadIdx.x] += tv;
            __syncthreads();
        }
        int excl = carry + s[threadIdx.x] - v;
        if (i < nb) bsum[i] = excl;
        __syncthreads();
        if (threadIdx.x == 0) carry += s[255];
        __syncthreads();
    }
}

// scan3v seeds the fill cursors (cur = rowptr start), so the fill needs
// only ONE atomic per edge (no separate rowptr read + counter).
__global__ __launch_bounds__(256) void scan3v(const int* __restrict__ cntd,
                                              const int* __restrict__ cnts,
                                              const int* __restrict__ bsumd,
                                              const int* __restrict__ bsums,
                                              int* __restrict__ rpd, int* __restrict__ rps,
                                              int* __restrict__ curd, int* __restrict__ curs,
                                              int N, int Ed, int Es) {
    const int g = blockIdx.y;
    const int* cnt = g ? cnts : cntd;
    const int* bsum = g ? bsums : bsumd;
    int* rowptr = g ? rps : rpd;
    int* cur = g ? curs : curd;
    const int E = g ? Es : Ed;
    __shared__ int s[256];
    int i = blockIdx.x * 256 + threadIdx.x;
    int v = (i < N) ? cnt[i] : 0;
    s[threadIdx.x] = v;
    __syncthreads();
    for (int o = 1; o < 256; o <<= 1) {
        int tv = (threadIdx.x >= o) ? s[threadIdx.x - o] : 0;
        __syncthreads();
        s[threadIdx.x] += tv;
        __syncthreads();
    }
    if (i < N) {
        const int st = bsum[blockIdx.x] + s[threadIdx.x] - v;
        rowptr[i] = st;
        cur[i] = st;
    }
    if (i == 0 && blockIdx.x == 0) rowptr[N] = E;
}

// ---------------------------------------------------------------------------
// XCD-binned CSR fill (round-2 verified win).
// ---------------------------------------------------------------------------
__global__ __launch_bounds__(256) void fill2b(const int* __restrict__ de,
                                              const int* __restrict__ se,
                                              int* __restrict__ curd, int* __restrict__ curs,
                                              int* __restrict__ sid, int* __restrict__ sis,
                                              int Ed, int Es, int N) {
    const int g = blockIdx.y;
    const int* ei = g ? se : de;
    int* cur = g ? curs : curd;
    int* srcidx = g ? sis : sid;
    const int E = g ? Es : Ed;
    const int nchunk = gridDim.x >> 3;
    const int bin = blockIdx.x & 7;
    const int chunk = blockIdx.x >> 3;
    const int BS = (N + 7) >> 3;
    const int dlo = bin * BS;
    const int dhi = min(N, dlo + BS);
    const int ce = (E + nchunk - 1) / nchunk;
    const int elo = chunk * ce;
    const int ehi = min(E, elo + ce);
    for (int e = elo + (int)threadIdx.x; e < ehi; e += 256) {
        const int dst = ei[E + e];
        if (dst >= dlo && dst < dhi) {
            const int pos = atomicAdd(&cur[dst], 1);
            srcidx[pos] = ei[e];
        }
    }
}

// ---------------------------------------------------------------------------
// Atom encoder: h = x @ aW + ab  (fp32 compute, bf16 store). grid.z = slot.
// Flat layout [slot][N][128].
// ---------------------------------------------------------------------------
__global__ void atom_kernel(const float* __restrict__ dx, const float* __restrict__ sx,
                            const float* __restrict__ aW, const float* __restrict__ ab,
                            u16* __restrict__ h, int N) {
    const int slot = blockIdx.z;
    long idx = (long)blockIdx.x * blockDim.x + threadIdx.x;
    if (idx >= (long)N * HID) return;
    const int n = (int)(idx / HID), c = (int)(idx % HID);
    const float* x = (slot < 2) ? dx : sx;
    const float* W = aW + (size_t)slot * 9 * HID;
    float acc = ab[slot * HID + c];
#pragma unroll
    for (int k = 0; k < 9; k++) acc = fmaf(x[n * 9 + k], W[k * HID + c], acc);
    h[(size_t)slot * N * HID + idx] = f2bf(acc);
}

// ---------------------------------------------------------------------------
// Gather-aggregate: z[n] = (1+eps)*h[n] + sum h[src].  ROUND-2 EXACT.
// At its random-access roofline (3.76 TB/s effective). Do not touch.
// ---------------------------------------------------------------------------
__global__ __launch_bounds__(256) void gather_agg(
    const int* __restrict__ rpd, const int* __restrict__ sid,
    const int* __restrict__ rps, const int* __restrict__ sis,
    const u16* __restrict__ h, u16* __restrict__ z,
    const float* __restrict__ eps, int N, int l) {
    const int slot = blockIdx.z;
    const int node = blockIdx.x * 16 + (threadIdx.x >> 4);
    if (node >= N) return;
    const int lane = threadIdx.x & 63;
    const int sl = lane & 15;
    const int subbase = lane & 48;  // 16-lane subgroup base within wave
    const int* rowptr = (slot < 2) ? rpd : rps;
    const int* srcidx = (slot < 2) ? sid : sis;
    const int lo = rowptr[node], hi = rowptr[node + 1];
    const u16* hp = h + (size_t)slot * N * HID;
    const int coff = sl * 8;

    u16x8 hv = *(const u16x8*)(hp + (size_t)node * HID + coff);
    const float scale = 1.f + eps[slot * NLAYER + l];
    float s[8];
#pragma unroll
    for (int i = 0; i < 8; i++) s[i] = bf2f(hv[i]) * scale;

    for (int base = lo; base < hi; base += 16) {
        const int cnt = min(16, hi - base);
        int idx = (sl < cnt) ? srcidx[base + sl] : 0;
        int j = 0;
        for (; j + 4 <= cnt; j += 4) {
            const int s0 = __shfl(idx, subbase + j);
            const int s1 = __shfl(idx, subbase + j + 1);
            const int s2 = __shfl(idx, subbase + j + 2);
            const int s3 = __shfl(idx, subbase + j + 3);
            u16x8 v0 = *(const u16x8*)(hp + (size_t)s0 * HID + coff);
            u16x8 v1 = *(const u16x8*)(hp + (size_t)s1 * HID + coff);
            u16x8 v2 = *(const u16x8*)(hp + (size_t)s2 * HID + coff);
            u16x8 v3 = *(const u16x8*)(hp + (size_t)s3 * HID + coff);
#pragma unroll
            for (int i = 0; i < 8; i++)
                s[i] += (bf2f(v0[i]) + bf2f(v1[i])) + (bf2f(v2[i]) + bf2f(v3[i]));
        }
        for (; j < cnt; j++) {
            const int sj = __shfl(idx, subbase + j);
            u16x8 v = *(const u16x8*)(hp + (size_t)sj * HID + coff);
#pragma unroll
            for (int i = 0; i < 8; i++) s[i] += bf2f(v[i]);
        }
    }
    u16x8 o;
#pragma unroll
    for (int i = 0; i < 8; i++) o[i] = f2bf(s[i]);
    *(u16x8*)(z + (size_t)slot * N * HID + (size_t)node * HID + coff) = o;
}

// ---------------------------------------------------------------------------
// Fused GIN layer: h_out = relu(BN2( relu(BN1(z@W1+b1)) @ W2 + b2 ))
// Round-6 structure (LDS weight staging, verified -44us) + T14 async-split:
// W1h1/W2p0/W2p1 global loads are issued one compute phase EARLY into regs,
// and all barriers are lgkmcnt-only raw barriers (cross-wave deps here are
// LDS-only), so prefetched loads stay in flight across barriers instead of
// being drained by __syncthreads()'s vmcnt(0). Math order bitwise = round 6.
// MFMA 16x16x32 bf16, C/D: col=lane&15, row=(lane>>4)*4+reg [m89-verified].
// ---------------------------------------------------------------------------
__global__ __launch_bounds__(256, 2) void fused_layer(
    const u16* __restrict__ A, const u16* __restrict__ W1t, const u16* __restrict__ W2t,
    const float* __restrict__ b1, const float* __restrict__ g1, const float* __restrict__ be1,
    const float* __restrict__ m1, const float* __restrict__ v1,
    const float* __restrict__ b2, const float* __restrict__ g2, const float* __restrict__ be2,
    const float* __restrict__ m2, const float* __restrict__ v2,
    u16* __restrict__ out, int M, int l) {

    const int slot = blockIdx.z;
    const int m0 = blockIdx.x * 128;
    const u16* Ap  = A + (size_t)slot * M * 128;
    const int el = slot * NLAYER + l;
    const u16* Wp1 = W1t + (size_t)el * (256 * 128);
    const u16* Wp2 = W2t + (size_t)el * (128 * 256);
    const size_t poff1 = (size_t)el * 256;
    const size_t poff2 = (size_t)el * 128;

    __shared__ u16 smz[128 * 136];  // 34.8 KB: z, then z2 halves
    __shared__ u16 smw[256 * 72];   // 36.9 KB: W1 K-half [256][72] / W2 K-half [128][136]

    const int tid = threadIdx.x;
    const int lane = tid & 63;
    const int w = tid >> 6;
    const int sl = lane & 15;
    const int k8 = lane >> 4;

    // staging chunk coordinates (same for all W stages)
    const int w1row[8] = { (0*256+tid)>>3, (1*256+tid)>>3, (2*256+tid)>>3, (3*256+tid)>>3,
                           (4*256+tid)>>3, (5*256+tid)>>3, (6*256+tid)>>3, (7*256+tid)>>3 };
    const int w1kc = tid & 7;        // (it*256+tid)&7 == tid&7
    const int w2kc = tid & 15;       // (it*256+tid)&15 == tid&15

    // ---- stage z tile + W1 K-half 0; prefetch W1 K-half 1 into regs ----
    {
        const int rp = tid >> 4;
        const int kc = (tid & 15) * 8;
#pragma unroll
        for (int p = 0; p < 8; p++) {
            const int row = p * 16 + rp;
            int gr = m0 + row; if (gr >= M) gr = M - 1;
            *(uint4*)&smz[row * 136 + kc] = *(const uint4*)(Ap + (size_t)gr * 128 + kc);
        }
    }
#pragma unroll
    for (int it = 0; it < 8; it++)
        *(uint4*)&smw[w1row[it] * 72 + w1kc * 8] =
            *(const uint4*)(Wp1 + (size_t)w1row[it] * 128 + w1kc * 8);
    uint4 pw[8];
#pragma unroll
    for (int it = 0; it < 8; it++)
        pw[it] = *(const uint4*)(Wp1 + (size_t)w1row[it] * 128 + 64 + w1kc * 8);
    BARRIER_LDS();  // sync1: z + W1h0 visible (pw loads stay in flight)

    // ---- GEMM1: 128 x 256, K=128, two K-halves (B from LDS) ----
    floatx4 acc1[8][4];
#pragma unroll
    for (int mt = 0; mt < 8; mt++)
#pragma unroll
        for (int c = 0; c < 4; c++) acc1[mt][c] = (floatx4)0.f;

    // K-half 0 (ks = 0,1)
#pragma unroll
    for (int ksl = 0; ksl < 2; ksl++) {
        const int ks = ksl;
        short8 a[8], b[4];
#pragma unroll
        for (int mt = 0; mt < 8; mt++)
            a[mt] = *(const short8*)&smz[(mt * 16 + sl) * 136 + ks * 32 + k8 * 8];
#pragma unroll
        for (int c = 0; c < 4; c++) {
            const int n = (c * 4 + w) * 16 + sl;
            b[c] = *(const short8*)&smw[n * 72 + ksl * 32 + k8 * 8];
        }
#pragma unroll
        for (int mt = 0; mt < 8; mt++)
#pragma unroll
            for (int c = 0; c < 4; c++)
                acc1[mt][c] = __builtin_amdgcn_mfma_f32_16x16x32_bf16(a[mt], b[c], acc1[mt][c], 0, 0, 0);
    }
    BARRIER_LDS();  // sync2: all waves done reading smw h0

    // write prefetched W1h1; prefetch W2 part0
#pragma unroll
    for (int it = 0; it < 8; it++)
        *(uint4*)&smw[w1row[it] * 72 + w1kc * 8] = pw[it];
#pragma unroll
    for (int it = 0; it < 8; it++) {
        const int row = (it * 256 + tid) >> 4;
        pw[it] = *(const uint4*)(Wp2 + (size_t)row * 256 + w2kc * 8);
    }
    BARRIER_LDS();  // sync3: W1h1 visible

    // K-half 1 (ks = 2,3)
#pragma unroll
    for (int ksl = 0; ksl < 2; ksl++) {
        const int ks = 2 + ksl;
        short8 a[8], b[4];
#pragma unroll
        for (int mt = 0; mt < 8; mt++)
            a[mt] = *(const short8*)&smz[(mt * 16 + sl) * 136 + ks * 32 + k8 * 8];
#pragma unroll
        for (int c = 0; c < 4; c++) {
            const int n = (c * 4 + w) * 16 + sl;
            b[c] = *(const short8*)&smw[n * 72 + ksl * 32 + k8 * 8];
        }
#pragma unroll
        for (int mt = 0; mt < 8; mt++)
#pragma unroll
            for (int c = 0; c < 4; c++)
                acc1[mt][c] = __builtin_amdgcn_mfma_f32_16x16x32_bf16(a[mt], b[c], acc1[mt][c], 0, 0, 0);
    }
    BARRIER_LDS();  // sync4: z + W1 reads done

    // ---- z2 halves + GEMM2 (B from LDS) ----
    const int wr = w & 1, wc = w >> 1;
    floatx4 acc2[4][4];
#pragma unroll
    for (int mt = 0; mt < 4; mt++)
#pragma unroll
        for (int nt = 0; nt < 4; nt++) acc2[mt][nt] = (floatx4)0.f;

#pragma unroll
    for (int part = 0; part < 2; part++) {
        // write z2 cols [part*128, part*128+128) after BN1+ReLU
#pragma unroll
        for (int c = part * 2; c < part * 2 + 2; c++) {
            const int gcol = (c * 4 + w) * 16 + sl;
            const int lcol = gcol - part * 128;
            const float sc = g1[poff1 + gcol] * rsqrtf(v1[poff1 + gcol] + 1e-5f);
            const float sh = (b1[poff1 + gcol] - m1[poff1 + gcol]) * sc + be1[poff1 + gcol];
#pragma unroll
            for (int mt = 0; mt < 8; mt++) {
#pragma unroll
                for (int r = 0; r < 4; r++) {
                    const int m = mt * 16 + k8 * 4 + r;
                    smz[m * 136 + lcol] = f2bf(fmaxf(fmaf(acc1[mt][c][r], sc, sh), 0.f));
                }
            }
        }
        // write prefetched W2 part; prefetch next W2 part (part 0 only)
#pragma unroll
        for (int it = 0; it < 8; it++) {
            const int row = (it * 256 + tid) >> 4;
            *(uint4*)&smw[row * 136 + w2kc * 8] = pw[it];
        }
        if (part == 0) {
#pragma unroll
            for (int it = 0; it < 8; it++) {
                const int row = (it * 256 + tid) >> 4;
                pw[it] = *(const uint4*)(Wp2 + (size_t)row * 256 + 128 + w2kc * 8);
            }
        }
        BARRIER_LDS();  // z2 half + W2 part visible
        // GEMM2 over this K half
#pragma unroll
        for (int ks = 0; ks < 4; ks++) {
            short8 a[4], b[4];
#pragma unroll
            for (int mt = 0; mt < 4; mt++)
                a[mt] = *(const short8*)&smz[(wr * 64 + mt * 16 + sl) * 136 + ks * 32 + k8 * 8];
#pragma unroll
            for (int nt = 0; nt < 4; nt++) {
                const int n = wc * 64 + nt * 16 + sl;
                b[nt] = *(const short8*)&smw[n * 136 + ks * 32 + k8 * 8];
            }
#pragma unroll
            for (int mt = 0; mt < 4; mt++)
#pragma unroll
                for (int nt = 0; nt < 4; nt++)
                    acc2[mt][nt] = __builtin_amdgcn_mfma_f32_16x16x32_bf16(a[mt], b[nt], acc2[mt][nt], 0, 0, 0);
        }
        if (part == 0) BARRIER_LDS();  // before overwriting smz/smw
    }

    // ---- BN2 + ReLU epilogue ----
    u16* outp = out + (size_t)slot * M * 128;
#pragma unroll
    for (int nt = 0; nt < 4; nt++) {
        const int col = wc * 64 + nt * 16 + sl;
        const float sc = g2[poff2 + col] * rsqrtf(v2[poff2 + col] + 1e-5f);
        const float sh = (b2[poff2 + col] - m2[poff2 + col]) * sc + be2[poff2 + col];
#pragma unroll
        for (int mt = 0; mt < 4; mt++) {
#pragma unroll
            for (int r = 0; r < 4; r++) {
                const int gr = m0 + wr * 64 + mt * 16 + k8 * 4 + r;
                if (gr < M)
                    outp[(size_t)gr * 128 + col] = f2bf(fmaxf(fmaf(acc2[mt][nt][r], sc, sh), 0.f));
            }
        }
    }
}

// ---------------------------------------------------------------------------
// Segment-mean pool (bat sorted). bf16 in, fp32 out.
// ---------------------------------------------------------------------------
__global__ __launch_bounds__(128) void pool_kernel(const int* __restrict__ db,
                                                   const int* __restrict__ sb,
                                                   const u16* __restrict__ h,
                                                   float* __restrict__ emb,
                                                   int N, int B) {
    const int slot = blockIdx.z;
    const int* bat = (slot < 2) ? db : sb;
    const int g = blockIdx.x;
    const int lo = lowbound(bat, N, g);
    const int hi = lowbound(bat, N, g + 1);
    const int c = threadIdx.x;
    float s = 0.f;
    const u16* hp = h + (size_t)slot * N * HID;
    for (int n = lo; n < hi; n++) s += bf2f(hp[(size_t)n * HID + c]);
    const float cnt = (float)(hi - lo);
    emb[((size_t)slot * B + g) * HID + c] = s / fmaxf(cnt, 1.f);
}

// ---------------------------------------------------------------------------
__device__ __forceinline__ float block_sum128(float x, float* red, int tid) {
    red[tid] = x;
    __syncthreads();
    if (tid < 64) {
        float v = red[tid] + red[tid + 64];
#pragma unroll
        for (int o = 32; o > 0; o >>= 1) v += __shfl_down(v, o);
        if (tid == 0) red[0] = v;
    }
    __syncthreads();
    float r = red[0];
    __syncthreads();
    return r;
}

// ---------------------------------------------------------------------------
// Fusion head (fp32)
// ---------------------------------------------------------------------------
__global__ __launch_bounds__(128) void fusion_kernel(
    const float* __restrict__ emb, const float* __restrict__ t,
    const float* __restrict__ tW1, const float* __restrict__ tb1,
    const float* __restrict__ tW2, const float* __restrict__ tb2,
    const float* __restrict__ iW, const float* __restrict__ ib,
    const float* __restrict__ ilg, const float* __restrict__ ilb,
    const float* __restrict__ fW1, const float* __restrict__ fb1,
    const float* __restrict__ l1g, const float* __restrict__ l1b,
    const float* __restrict__ fW2, const float* __restrict__ fb2,
    const float* __restrict__ l2g, const float* __restrict__ l2b,
    const float* __restrict__ fW3, const float* __restrict__ fb3,
    float* __restrict__ out, int B) {
    const int r = blockIdx.x;
    const int tid = threadIdx.x;
    __shared__ float cs[256];
    __shared__ float cat[288];
    __shared__ float buf[128];
    __shared__ float red[128];
    __shared__ float tmp32[32];

    cs[tid]        = emb[((size_t)1 * B + r) * HID + tid];
    cs[128 + tid]  = emb[((size_t)2 * B + r) * HID + tid];
    cat[tid]       = emb[((size_t)0 * B + r) * HID + tid];
    __syncthreads();

    float acc = ib[tid];
    for (int k = 0; k < 256; k++) acc = fmaf(cs[k], iW[k * HID + tid], acc);
    float mu  = block_sum128(acc, red, tid) * (1.f / 128.f);
    float d   = acc - mu;
    float var = block_sum128(d * d, red, tid) * (1.f / 128.f);
    float inter = fmaxf(d * rsqrtf(var + 1e-5f) * ilg[tid] + ilb[tid], 0.f);
    cat[128 + tid] = inter;

    if (tid < 32) tmp32[tid] = fmaxf(fmaf(t[r], tW1[tid], tb1[tid]), 0.f);
    __syncthreads();
    if (tid < 32) {
        float a2 = tb2[tid];
        for (int j = 0; j < 32; j++) a2 = fmaf(tmp32[j], tW2[j * 32 + tid], a2);
        cat[256 + tid] = a2;
    }
    __syncthreads();

    float a1 = fb1[tid];
    for (int k = 0; k < 288; k++) a1 = fmaf(cat[k], fW1[k * HID + tid], a1);
    mu  = block_sum128(a1, red, tid) * (1.f / 128.f);
    d   = a1 - mu;
    var = block_sum128(d * d, red, tid) * (1.f / 128.f);
    buf[tid] = fmaxf(d * rsqrtf(var + 1e-5f) * l1g[tid] + l1b[tid], 0.f);
    __syncthreads();

    float a2v = 0.f;
    if (tid < 64) {
        a2v = fb2[tid];
        for (int k = 0; k < 128; k++) a2v = fmaf(buf[k], fW2[k * 64 + tid], a2v);
    }
    mu = block_sum128((tid < 64) ? a2v : 0.f, red, tid) * (1.f / 64.f);
    float d2 = (tid < 64) ? (a2v - mu) : 0.f;
    var = block_sum128(d2 * d2, red, tid) * (1.f / 64.f);
    float contrib = 0.f;
    if (tid < 64) {
        float h2 = fmaxf(d2 * rsqrtf(var + 1e-5f) * l2g[tid] + l2b[tid], 0.f);
        contrib = h2 * fW3[tid];
    }
    float s = block_sum128(contrib, red, tid);
    if (tid == 0) out[r] = s + fb3[0];
}

// ---------------------------------------------------------------------------
extern "C" void kernel_launch(void* const* d_in, const int* in_sizes, int n_in,
                              void* d_out, int out_size, void* d_ws, size_t ws_size,
                              hipStream_t stream) {
    const float* dx  = (const float*)d_in[0];
    const int*   de  = (const int*)d_in[1];
    const int*   db  = (const int*)d_in[2];
    const float* sx  = (const float*)d_in[3];
    const int*   se  = (const int*)d_in[4];
    const int*   sb  = (const int*)d_in[5];
    const float* t   = (const float*)d_in[6];
    const float* aW  = (const float*)d_in[7];
    const float* ab  = (const float*)d_in[8];
    const float* eps = (const float*)d_in[9];
    const float* W1  = (const float*)d_in[10];
    const float* b1  = (const float*)d_in[11];
    const float* g1  = (const float*)d_in[12];
    const float* be1 = (const float*)d_in[13];
    const float* m1  = (const float*)d_in[14];
    const float* v1  = (const float*)d_in[15];
    const float* W2  = (const float*)d_in[16];
    const float* b2  = (const float*)d_in[17];
    const float* g2  = (const float*)d_in[18];
    const float* be2 = (const float*)d_in[19];
    const float* m2  = (const float*)d_in[20];
    const float* v2  = (const float*)d_in[21];
    const float* tW1 = (const float*)d_in[22];
    const float* tb1 = (const float*)d_in[23];
    const float* tW2 = (const float*)d_in[24];
    const float* tb2 = (const float*)d_in[25];
    const float* iW  = (const float*)d_in[26];
    const float* ib  = (const float*)d_in[27];
    const float* ilg = (const float*)d_in[28];
    const float* ilb = (const float*)d_in[29];
    const float* fW1 = (const float*)d_in[30];
    const float* fb1 = (const float*)d_in[31];
    const float* l1g = (const float*)d_in[32];
    const float* l1b = (const float*)d_in[33];
    const float* fW2 = (const float*)d_in[34];
    const float* fb2 = (const float*)d_in[35];
    const float* l2g = (const float*)d_in[36];
    const float* l2b = (const float*)d_in[37];
    const float* fW3 = (const float*)d_in[38];
    const float* fb3 = (const float*)d_in[39];
    float* out = (float*)d_out;

    const int N  = in_sizes[0] / 9;
    const int Ed = in_sizes[1] / 2;
    const int Es = in_sizes[4] / 2;
    const int B  = in_sizes[6];
    const int nb = (N + 255) / 256;

    // ---- workspace layout ----
    char* w8 = (char*)d_ws;
    int* rpd   = (int*)w8;
    int* rps   = rpd + (N + 1);
    int* cntd  = rps + (N + 1);
    int* cnts  = cntd + N;
    int* curd  = cnts + N;   // fill cursors (seeded by scan3v)
    int* curs  = curd + N;
    int* sid   = curs + N;
    int* sis   = sid + Ed;
    int* bsumd = sis + Es;
    int* bsums = bsumd + nb;
    size_t int_bytes = ((char*)(bsums + nb)) - w8;
    size_t foff = (int_bytes + 255) & ~(size_t)255;

    const int WT = 3 * NLAYER * 128 * 256;
    u16* W1t = (u16*)(w8 + foff);
    u16* W2t = W1t + WT;
    const size_t hS = (size_t)N * HID;
    u16* hbuf = W2t + WT;
    u16* zbuf = hbuf + 3 * hS;
    float* emb = (float*)(((uintptr_t)(zbuf + 3 * hS) + 255) & ~(uintptr_t)255);

    // ---- weight prep + CSR build ----
    prep_weights<<<(2 * WT + 255) / 256, 256, 0, stream>>>(W1, W2, W1t, W2t);
    hipMemsetAsync(cntd, 0, (size_t)2 * N * sizeof(int), stream);
    {
        dim3 gb(128 * 8, 2);  // 128 edge-chunks x 8 dst-bins, both graphs
        hist2b<<<gb, 256, 0, stream>>>(de, se, cntd, cnts, Ed, Es, N);
        dim3 gs1(nb, 2);
        scan1v<<<gs1, 256, 0, stream>>>(cntd, cnts, bsumd, bsums, N);
        scan2v<<<2, 256, 0, stream>>>(bsumd, bsums, nb);
        scan3v<<<gs1, 256, 0, stream>>>(cntd, cnts, bsumd, bsums, rpd, rps, curd, curs, N, Ed, Es);
        fill2b<<<gb, 256, 0, stream>>>(de, se, curd, curs, sid, sis, Ed, Es, N);
    }

    // ---- encoders (all 3 slots batched via grid.z) ----
    {
        dim3 ga((N * HID + 255) / 256, 1, 3);
        atom_kernel<<<ga, 256, 0, stream>>>(dx, sx, aW, ab, hbuf, N);
        for (int l = 0; l < NLAYER; l++) {
            dim3 gg((N + 15) / 16, 1, 3);
            gather_agg<<<gg, 256, 0, stream>>>(rpd, sid, rps, sis, hbuf, zbuf, eps, N, l);
            dim3 gf((N + 127) / 128, 1, 3);
            fused_layer<<<gf, 256, 0, stream>>>(zbuf, W1t, W2t,
                                                b1, g1, be1, m1, v1,
                                                b2, g2, be2, m2, v2,
                                                hbuf, N, l);
        }
        dim3 gp(B, 1, 3);
        pool_kernel<<<gp, 128, 0, stream>>>(db, sb, hbuf, emb, N, B);
    }
    fusion_kernel<<<B, 128, 0, stream>>>(emb, t, tW1, tb1, tW2, tb2,
                                         iW, ib, ilg, ilb, fW1, fb1, l1g, l1b,
                                         fW2, fb2, l2g, l2b, fW3, fb3, out, B);
}